// Round 2
// baseline (2412.480 us; speedup 1.0000x reference)
//
#include <hip/hip_runtime.h>
#include <hip/hip_bf16.h>
#include <cstdint>
#include <cstddef>

// Problem: out[b,o] = sum_i silu(x[b,i])*BW[o,i] + sum_{i,c} exp(-5*(x[b,i]-g_c)^2)*SW[o,i,c]
//   x: [16384, 2048] f32, BW: [2048, 2048] f32, SW: [2048, 2048, 5] f32, out: [16384,2048] f32
// Treated as GEMM C = A * W^T with expanded K = 2048*6 = 12288 (k-order per 16-feature
// tile: [i_rel*5 + c] spline block (80), then [80 + i_rel] silu block (16) => BK=96).
// Round 1 retry: identical structure to round 0 (infra flake, no bench data);
// __builtin_amdgcn_rcpf replaced by plain divide as the only hardening change.

#define BM 128
#define BN 128
#define NF 16          // input features per K-iteration
#define BK 96          // expanded k per iteration (NF*6)
#define LDK 104        // padded LDS row stride in bf16 elements (BK + 8)
#define KIN 2048
#define NOUT 2048

typedef __bf16 bf16x8 __attribute__((ext_vector_type(8)));
typedef float f32x4 __attribute__((ext_vector_type(4)));
typedef unsigned short u16x4 __attribute__((ext_vector_type(4)));

__device__ __forceinline__ unsigned short f2bf(float f) {
    union { float f; uint32_t u; } v; v.f = f;
    return (unsigned short)((v.u + 0x7FFFu + ((v.u >> 16) & 1u)) >> 16);
}

__global__ __launch_bounds__(256)
void kan_fused(const float* __restrict__ X, const float* __restrict__ BW,
               const float* __restrict__ SW, float* __restrict__ OUT)
{
    __shared__ __align__(16) unsigned short As[BM * LDK];
    __shared__ __align__(16) unsigned short Bs[BN * LDK];

    const int tid  = threadIdx.x;
    const int lane = tid & 63;
    const int wave = tid >> 6;
    const int mt = blockIdx.x >> 4;   // 128 m-tiles
    const int nt = blockIdx.x & 15;   // 16 n-tiles
    const int m0 = mt * BM;
    const int n0 = nt * BN;
    const int r    = lane & 15;
    const int quad = lane >> 4;
    const int wm = (wave & 1) * 64;
    const int wn = (wave >> 1) * 64;

    f32x4 acc[4][4];
    #pragma unroll
    for (int i = 0; i < 4; ++i)
        #pragma unroll
        for (int j = 0; j < 4; ++j)
            acc[i][j] = (f32x4){0.0f, 0.0f, 0.0f, 0.0f};

    for (int it = 0; it < KIN / NF; ++it) {
        const int i0 = it * NF;
        __syncthreads();   // protect LDS against previous iteration's readers

        // ---------------- stage A: x[m0..+127][i0..+15] -> silu + 5 RBF ----------------
        #pragma unroll
        for (int s = 0; s < 2; ++s) {
            const int slot = tid + s * 256;          // 0..511 float4 slots
            const int row  = slot >> 2;              // 0..127
            const int fq   = slot & 3;               // feature quad
            const f32x4 xv = *(const f32x4*)(X + (size_t)(m0 + row) * KIN + i0 + fq * 4);
            unsigned short basv[20];
            unsigned short silv[4];
            #pragma unroll
            for (int e = 0; e < 4; ++e) {
                const float xf = xv[e];
                silv[e] = f2bf(xf / (1.0f + __expf(-xf)));
                #pragma unroll
                for (int c = 0; c < 5; ++c) {
                    const float d = xf - (-1.0f + 0.5f * (float)c);
                    basv[e * 5 + c] = f2bf(__expf(-5.0f * d * d));
                }
            }
            unsigned short* dst = As + row * LDK + fq * 20;   // spline block [0,80)
            #pragma unroll
            for (int q = 0; q < 5; ++q) {
                u16x4 v;
                v.x = basv[q * 4 + 0]; v.y = basv[q * 4 + 1];
                v.z = basv[q * 4 + 2]; v.w = basv[q * 4 + 3];
                *(u16x4*)(dst + q * 4) = v;
            }
            u16x4 sv;
            sv.x = silv[0]; sv.y = silv[1]; sv.z = silv[2]; sv.w = silv[3];
            *(u16x4*)(As + row * LDK + 80 + fq * 4) = sv;     // silu block [80,96)
        }

        // ---------------- stage B: spline weights (80 contiguous f32 per o-row) --------
        {
            const int orow = tid >> 1;               // 0..127
            const int half = tid & 1;                // which 8-feature half
            const float* sbase = SW + (size_t)(n0 + orow) * (KIN * 5) + i0 * 5 + half * 40;
            unsigned short* brow = Bs + orow * LDK + half * 40;
            #pragma unroll
            for (int p = 0; p < 10; ++p) {
                const f32x4 wv = *(const f32x4*)(sbase + p * 4);
                u16x4 v;
                v.x = f2bf(wv.x); v.y = f2bf(wv.y);
                v.z = f2bf(wv.z); v.w = f2bf(wv.w);
                *(u16x4*)(brow + p * 4) = v;
            }
        }

        // ---------------- stage B: base weights ----------------
        #pragma unroll
        for (int s = 0; s < 2; ++s) {
            const int slot = tid + s * 256;
            const int row  = slot >> 2;
            const int fq   = slot & 3;
            const f32x4 wv = *(const f32x4*)(BW + (size_t)(n0 + row) * KIN + i0 + fq * 4);
            u16x4 v;
            v.x = f2bf(wv.x); v.y = f2bf(wv.y);
            v.z = f2bf(wv.z); v.w = f2bf(wv.w);
            *(u16x4*)(Bs + row * LDK + 80 + fq * 4) = v;
        }

        __syncthreads();

        // ---------------- MFMA: 3 k-steps x (4x4) 16x16x32 tiles ----------------
        #pragma unroll
        for (int ks = 0; ks < 3; ++ks) {
            bf16x8 af[4], bfr[4];
            #pragma unroll
            for (int mi = 0; mi < 4; ++mi)
                af[mi] = *(const bf16x8*)(As + (wm + mi * 16 + r) * LDK + ks * 32 + quad * 8);
            #pragma unroll
            for (int ni = 0; ni < 4; ++ni)
                bfr[ni] = *(const bf16x8*)(Bs + (wn + ni * 16 + r) * LDK + ks * 32 + quad * 8);
            #pragma unroll
            for (int mi = 0; mi < 4; ++mi)
                #pragma unroll
                for (int ni = 0; ni < 4; ++ni)
                    acc[mi][ni] = __builtin_amdgcn_mfma_f32_16x16x32_bf16(
                        af[mi], bfr[ni], acc[mi][ni], 0, 0, 0);
        }
    }

    // ---------------- epilogue: C/D layout col=lane&15, row=quad*4+reg ----------------
    #pragma unroll
    for (int mi = 0; mi < 4; ++mi) {
        #pragma unroll
        for (int ni = 0; ni < 4; ++ni) {
            const int col  = n0 + wn + ni * 16 + r;
            const int rowb = m0 + wm + mi * 16 + quad * 4;
            #pragma unroll
            for (int reg = 0; reg < 4; ++reg)
                OUT[(size_t)(rowb + reg) * NOUT + col] = acc[mi][ni][reg];
        }
    }
}

extern "C" void kernel_launch(void* const* d_in, const int* in_sizes, int n_in,
                              void* d_out, int out_size, void* d_ws, size_t ws_size,
                              hipStream_t stream) {
    const float* X  = (const float*)d_in[0];
    const float* BW = (const float*)d_in[1];
    const float* SW = (const float*)d_in[2];
    float* OUT = (float*)d_out;
    // grid: 128 m-tiles * 16 n-tiles; consecutive blocks share an m-tile (x slab reuse in L2)
    kan_fused<<<dim3(128 * 16), dim3(256), 0, stream>>>(X, BW, SW, OUT);
}

// Round 3
// 1418.965 us; speedup vs baseline: 1.7002x; 1.7002x over previous
//
#include <hip/hip_runtime.h>
#include <hip/hip_bf16.h>
#include <cstdint>
#include <cstddef>

// out[b,o] = sum_i silu(x[b,i])*BW[o,i] + sum_{i,c} exp(-5*(x[b,i]-g_c)^2)*SW[o,i,c]
// Round 3: precompute expanded A [16384][12288] bf16 and W [2048][12288] bf16 into d_ws
// (k = i*6 + j; j in 0..4 = RBF c, j=5 = silu/base), then pure bf16 MFMA GEMM with
// global_load_lds(16B) staging + XOR-swizzled LDS. Fallback to the validated round-2
// fused kernel if ws_size < 453 MB.

#define KIN 2048
#define NOUT 2048
#define BATCH 16384
#define KEXP 12288          // 2048 * 6

typedef __bf16 bf16x8 __attribute__((ext_vector_type(8)));
typedef float f32x4 __attribute__((ext_vector_type(4)));
typedef unsigned short u16x4 __attribute__((ext_vector_type(4)));

__device__ __forceinline__ unsigned short f2bf(float f) {
    union { float f; uint32_t u; } v; v.f = f;
    return (unsigned short)((v.u + 0x7FFFu + ((v.u >> 16) & 1u)) >> 16);
}

__device__ __forceinline__ void load_lds16(const void* gptr, void* lptr) {
    __builtin_amdgcn_global_load_lds(
        (const __attribute__((address_space(1))) unsigned int*)gptr,
        (__attribute__((address_space(3))) unsigned int*)lptr,
        16, 0, 0);
}

// ---------------- expansion: x -> Aexp (bf16, k = i*6 + j) ----------------
__global__ __launch_bounds__(256)
void expand_a(const float* __restrict__ X, __bf16* __restrict__ Aexp)
{
    const int idx = blockIdx.x * 256 + threadIdx.x;   // 16384 * 512
    const int row = idx >> 9;
    const int g   = idx & 511;                        // 4-feature group
    const f32x4 xv = *(const f32x4*)(X + (size_t)row * KIN + g * 4);
    __bf16 o[24];
    #pragma unroll
    for (int e = 0; e < 4; ++e) {
        const float xf = xv[e];
        #pragma unroll
        for (int c = 0; c < 5; ++c) {
            const float d = xf - (-1.0f + 0.5f * (float)c);
            o[e * 6 + c] = (__bf16)__expf(-5.0f * d * d);
        }
        o[e * 6 + 5] = (__bf16)(xf / (1.0f + __expf(-xf)));
    }
    __bf16* dst = Aexp + (size_t)row * KEXP + g * 24;
    #pragma unroll
    for (int q = 0; q < 3; ++q) {
        bf16x8 v;
        #pragma unroll
        for (int t = 0; t < 8; ++t) v[t] = o[q * 8 + t];
        *(bf16x8*)(dst + q * 8) = v;
    }
}

// ---------------- expansion: BW/SW -> Wexp (bf16, same k order) ----------------
__global__ __launch_bounds__(256)
void expand_w(const float* __restrict__ BW, const float* __restrict__ SW,
              __bf16* __restrict__ Wexp)
{
    const int idx = blockIdx.x * 256 + threadIdx.x;   // 2048 * 512
    const int orow = idx >> 9;
    const int g    = idx & 511;
    const int i0   = g * 4;
    const float* sb = SW + ((size_t)orow * KIN + i0) * 5;   // 20 contiguous floats
    const f32x4 bw = *(const f32x4*)(BW + (size_t)orow * KIN + i0);
    float sw[20];
    #pragma unroll
    for (int q = 0; q < 5; ++q) {
        const f32x4 v = *(const f32x4*)(sb + q * 4);
        sw[q * 4 + 0] = v.x; sw[q * 4 + 1] = v.y; sw[q * 4 + 2] = v.z; sw[q * 4 + 3] = v.w;
    }
    __bf16 o[24];
    #pragma unroll
    for (int e = 0; e < 4; ++e) {
        #pragma unroll
        for (int c = 0; c < 5; ++c) o[e * 6 + c] = (__bf16)sw[e * 5 + c];
        o[e * 6 + 5] = (__bf16)bw[e];
    }
    __bf16* dst = Wexp + (size_t)orow * KEXP + g * 24;
    #pragma unroll
    for (int q = 0; q < 3; ++q) {
        bf16x8 v;
        #pragma unroll
        for (int t = 0; t < 8; ++t) v[t] = o[q * 8 + t];
        *(bf16x8*)(dst + q * 8) = v;
    }
}

// ---------------- pure bf16 GEMM: OUT[16384][2048] = Aexp * Wexp^T ----------------
// 128x128 tile, BK=64, 4 waves x (64x64), global_load_lds 16B, XOR chunk swizzle.
__global__ __launch_bounds__(256)
void gemm_bf16(const __bf16* __restrict__ A, const __bf16* __restrict__ W,
               float* __restrict__ OUT)
{
    __shared__ __align__(16) __bf16 As[128 * 64];   // 16 KB, chunk-swizzled
    __shared__ __align__(16) __bf16 Bs[128 * 64];   // 16 KB

    const int tid  = threadIdx.x;
    const int lane = tid & 63;
    const int wave = tid >> 6;
    const int mt = blockIdx.x >> 4;    // 128 m-tiles
    const int nt = blockIdx.x & 15;    // 16 n-tiles
    const int m0 = mt * 128;
    const int n0 = nt * 128;
    const int r    = lane & 15;
    const int quad = lane >> 4;
    const int wm = (wave & 1) * 64;
    const int wn = (wave >> 1) * 64;

    f32x4 acc[4][4];
    #pragma unroll
    for (int i = 0; i < 4; ++i)
        #pragma unroll
        for (int j = 0; j < 4; ++j)
            acc[i][j] = (f32x4){0.0f, 0.0f, 0.0f, 0.0f};

    for (int kt = 0; kt < KEXP / 64; ++kt) {
        const int k0 = kt * 64;
        __syncthreads();
        // stage A + B: 4 + 4 issues of 16B/lane. chunk c -> (row = c>>3, physcol = c&7),
        // logical col j = physcol ^ (row & 7); global source = row-major [row][k0 + j*8].
        #pragma unroll
        for (int s = 0; s < 4; ++s) {
            const int c   = tid + s * 256;
            const int row = c >> 3;
            const int j   = (c & 7) ^ (row & 7);
            load_lds16(A + (size_t)(m0 + row) * KEXP + k0 + j * 8,
                       As + (s * 256 + wave * 64) * 8);
        }
        #pragma unroll
        for (int s = 0; s < 4; ++s) {
            const int c   = tid + s * 256;
            const int row = c >> 3;
            const int j   = (c & 7) ^ (row & 7);
            load_lds16(W + (size_t)(n0 + row) * KEXP + k0 + j * 8,
                       Bs + (s * 256 + wave * 64) * 8);
        }
        __syncthreads();

        #pragma unroll
        for (int ks = 0; ks < 2; ++ks) {
            bf16x8 af[4], bfr[4];
            #pragma unroll
            for (int mi = 0; mi < 4; ++mi) {
                const int row = wm + mi * 16 + r;
                af[mi] = *(const bf16x8*)(As + row * 64 + ((ks * 4 + quad) ^ (r & 7)) * 8);
            }
            #pragma unroll
            for (int ni = 0; ni < 4; ++ni) {
                const int row = wn + ni * 16 + r;
                bfr[ni] = *(const bf16x8*)(Bs + row * 64 + ((ks * 4 + quad) ^ (r & 7)) * 8);
            }
            #pragma unroll
            for (int mi = 0; mi < 4; ++mi)
                #pragma unroll
                for (int ni = 0; ni < 4; ++ni)
                    acc[mi][ni] = __builtin_amdgcn_mfma_f32_16x16x32_bf16(
                        af[mi], bfr[ni], acc[mi][ni], 0, 0, 0);
        }
    }

    // epilogue: C/D layout col = lane&15, row = quad*4 + reg
    #pragma unroll
    for (int mi = 0; mi < 4; ++mi) {
        #pragma unroll
        for (int ni = 0; ni < 4; ++ni) {
            const int col  = n0 + wn + ni * 16 + r;
            const int rowb = m0 + wm + mi * 16 + quad * 4;
            #pragma unroll
            for (int reg = 0; reg < 4; ++reg)
                OUT[(size_t)(rowb + reg) * NOUT + col] = acc[mi][ni][reg];
        }
    }
}

// ---------------- fallback: validated round-2 fused kernel ----------------
#define BM 128
#define BN 128
#define NF 16
#define BK 96
#define LDK 104

__global__ __launch_bounds__(256)
void kan_fused(const float* __restrict__ X, const float* __restrict__ BW,
               const float* __restrict__ SW, float* __restrict__ OUT)
{
    __shared__ __align__(16) unsigned short As[BM * LDK];
    __shared__ __align__(16) unsigned short Bs[BN * LDK];

    const int tid  = threadIdx.x;
    const int lane = tid & 63;
    const int wave = tid >> 6;
    const int mt = blockIdx.x >> 4;
    const int nt = blockIdx.x & 15;
    const int m0 = mt * BM;
    const int n0 = nt * BN;
    const int r    = lane & 15;
    const int quad = lane >> 4;
    const int wm = (wave & 1) * 64;
    const int wn = (wave >> 1) * 64;

    f32x4 acc[4][4];
    #pragma unroll
    for (int i = 0; i < 4; ++i)
        #pragma unroll
        for (int j = 0; j < 4; ++j)
            acc[i][j] = (f32x4){0.0f, 0.0f, 0.0f, 0.0f};

    for (int it = 0; it < KIN / NF; ++it) {
        const int i0 = it * NF;
        __syncthreads();
        #pragma unroll
        for (int s = 0; s < 2; ++s) {
            const int slot = tid + s * 256;
            const int row  = slot >> 2;
            const int fq   = slot & 3;
            const f32x4 xv = *(const f32x4*)(X + (size_t)(m0 + row) * KIN + i0 + fq * 4);
            unsigned short basv[20];
            unsigned short silv[4];
            #pragma unroll
            for (int e = 0; e < 4; ++e) {
                const float xf = xv[e];
                silv[e] = f2bf(xf / (1.0f + __expf(-xf)));
                #pragma unroll
                for (int c = 0; c < 5; ++c) {
                    const float d = xf - (-1.0f + 0.5f * (float)c);
                    basv[e * 5 + c] = f2bf(__expf(-5.0f * d * d));
                }
            }
            unsigned short* dst = As + row * LDK + fq * 20;
            #pragma unroll
            for (int q = 0; q < 5; ++q) {
                u16x4 v;
                v.x = basv[q * 4 + 0]; v.y = basv[q * 4 + 1];
                v.z = basv[q * 4 + 2]; v.w = basv[q * 4 + 3];
                *(u16x4*)(dst + q * 4) = v;
            }
            u16x4 sv;
            sv.x = silv[0]; sv.y = silv[1]; sv.z = silv[2]; sv.w = silv[3];
            *(u16x4*)(As + row * LDK + 80 + fq * 4) = sv;
        }
        {
            const int orow = tid >> 1;
            const int half = tid & 1;
            const float* sbase = SW + (size_t)(n0 + orow) * (KIN * 5) + i0 * 5 + half * 40;
            unsigned short* brow = Bs + orow * LDK + half * 40;
            #pragma unroll
            for (int p = 0; p < 10; ++p) {
                const f32x4 wv = *(const f32x4*)(sbase + p * 4);
                u16x4 v;
                v.x = f2bf(wv.x); v.y = f2bf(wv.y);
                v.z = f2bf(wv.z); v.w = f2bf(wv.w);
                *(u16x4*)(brow + p * 4) = v;
            }
        }
        #pragma unroll
        for (int s = 0; s < 2; ++s) {
            const int slot = tid + s * 256;
            const int row  = slot >> 2;
            const int fq   = slot & 3;
            const f32x4 wv = *(const f32x4*)(BW + (size_t)(n0 + row) * KIN + i0 + fq * 4);
            u16x4 v;
            v.x = f2bf(wv.x); v.y = f2bf(wv.y);
            v.z = f2bf(wv.z); v.w = f2bf(wv.w);
            *(u16x4*)(Bs + row * LDK + 80 + fq * 4) = v;
        }
        __syncthreads();
        #pragma unroll
        for (int ks = 0; ks < 3; ++ks) {
            bf16x8 af[4], bfr[4];
            #pragma unroll
            for (int mi = 0; mi < 4; ++mi)
                af[mi] = *(const bf16x8*)(As + (wm + mi * 16 + r) * LDK + ks * 32 + quad * 8);
            #pragma unroll
            for (int ni = 0; ni < 4; ++ni)
                bfr[ni] = *(const bf16x8*)(Bs + (wn + ni * 16 + r) * LDK + ks * 32 + quad * 8);
            #pragma unroll
            for (int mi = 0; mi < 4; ++mi)
                #pragma unroll
                for (int ni = 0; ni < 4; ++ni)
                    acc[mi][ni] = __builtin_amdgcn_mfma_f32_16x16x32_bf16(
                        af[mi], bfr[ni], acc[mi][ni], 0, 0, 0);
        }
    }
    #pragma unroll
    for (int mi = 0; mi < 4; ++mi) {
        #pragma unroll
        for (int ni = 0; ni < 4; ++ni) {
            const int col  = n0 + wn + ni * 16 + r;
            const int rowb = m0 + wm + mi * 16 + quad * 4;
            #pragma unroll
            for (int reg = 0; reg < 4; ++reg)
                OUT[(size_t)(rowb + reg) * NOUT + col] = acc[mi][ni][reg];
        }
    }
}

extern "C" void kernel_launch(void* const* d_in, const int* in_sizes, int n_in,
                              void* d_out, int out_size, void* d_ws, size_t ws_size,
                              hipStream_t stream) {
    const float* X  = (const float*)d_in[0];
    const float* BW = (const float*)d_in[1];
    const float* SW = (const float*)d_in[2];
    float* OUT = (float*)d_out;

    const size_t nA = (size_t)BATCH * KEXP;          // 201,326,592 elems
    const size_t nW = (size_t)NOUT * KEXP;           //  25,165,824 elems
    const size_t ws_need = (nA + nW) * sizeof(__bf16);   // 452,984,832 B

    if (ws_size >= ws_need) {
        __bf16* Aexp = (__bf16*)d_ws;
        __bf16* Wexp = Aexp + nA;
        expand_a<<<dim3(BATCH * 512 / 256), dim3(256), 0, stream>>>(X, Aexp);
        expand_w<<<dim3(NOUT * 512 / 256), dim3(256), 0, stream>>>(BW, SW, Wexp);
        gemm_bf16<<<dim3(128 * 16), dim3(256), 0, stream>>>(Aexp, Wexp, OUT);
    } else {
        kan_fused<<<dim3(128 * 16), dim3(256), 0, stream>>>(X, BW, SW, OUT);
    }
}